// Round 11
// baseline (749.824 us; speedup 1.0000x reference)
//
#include <hip/hip_runtime.h>
#include <hip/hip_bf16.h>
#include <stdint.h>

#define T_TOK 16384
#define HD    1024
#define HD2   2048
#define NE    8
#define ROWS  (2*T_TOK)   // 32768 expert-row assignments (exactly 2 per token)
#define MAXT  264         // max M-tiles at 128 rows (gemm1)
#define MT256 136         // max M-tiles at 256 rows (gemm2)
#define RTOK  32          // tokens per router block
#define NCVT  65536       // cvt sub-blocks in fused front kernel (64x64x16)

// meta: ONLY per-expert counters, cnt[e] at meta[e*32] (cache-line padded).

typedef __bf16 bf16x8 __attribute__((ext_vector_type(8)));
typedef float f32x4 __attribute__((ext_vector_type(4)));
typedef unsigned short u16x8 __attribute__((ext_vector_type(8)));

// async 16B global->LDS (dest = wave-uniform base + lane*16)
#define GLD16(g, l) __builtin_amdgcn_global_load_lds( \
    (const __attribute__((address_space(1))) void*)(g), \
    (__attribute__((address_space(3))) void*)(l), 16, 0, 0)

__device__ inline unsigned short f2bf(float f) {  // RNE fp32->bf16
    unsigned int u = __float_as_uint(f);
    unsigned int r = (u + 0x7fffu + ((u >> 16) & 1u)) >> 16;
    return (unsigned short)r;
}

// ---- derive (e, r0, rend) for M-tile mt at GRAN rows; e=-1 if mt >= ntiles ----
__device__ inline void tile_locate_g(const int* __restrict__ meta, int mt, int gran_log2,
                                     int* e_out, int* r0_out, int* re_out) {
    int gran = 1 << gran_log2;
    int o = 0, tb = 0, se = -1, sr0 = 0, sre = 0;
#pragma unroll
    for (int k = 0; k < NE; k++) {
        int c = meta[k * 32];
        int t = (c + gran - 1) >> gran_log2;
        if (mt >= tb && mt < tb + t) {
            se = k;
            sr0 = o + (mt - tb) * gran;
            int re = o + c;
            sre = (sr0 + gran < re) ? sr0 + gran : re;
        }
        o += c; tb += t;
    }
    *e_out = se; *r0_out = sr0; *re_out = sre;
}

// ========== fused front kernel: weight transpose-convert + router ==========
// blocks [0, NCVT): cvt (z=id&15 -> expert/matrix; x,y from id>>4)
// blocks [NCVT, NCVT+512): router block bid = id - NCVT
__global__ __launch_bounds__(256) void front_k(
        const float* __restrict__ w1, const float* __restrict__ w2,
        unsigned short* __restrict__ W1T, unsigned short* __restrict__ W2T,
        const float* __restrict__ x, const float* __restrict__ gw,
        int* __restrict__ meta, int* __restrict__ tok_e, int* __restrict__ tok_slot,
        float* __restrict__ tok_w, unsigned short* __restrict__ xb) {
    __shared__ float smem[8400];   // union: cvt t[32][33] (1056) | router g[8192]+meta
    int id = blockIdx.x;
    if (id < NCVT) {
        // ---------------- cvt path ----------------
        int z = id & 15, rest = id >> 4;
        int bx = rest & 63, by = rest >> 6;
        const float* w; unsigned short* wt; int K, N, e;
        if (z < 8) { w = w1; wt = W1T; K = HD;  N = HD2; e = z; }
        else       { w = w2; wt = W2T; K = HD2; N = HD;  e = z - 8; }
        int n0 = bx * 32, k0 = by * 32;
        if (n0 >= N || k0 >= K) return;
        float (*t)[33] = (float(*)[33])smem;
        int r = threadIdx.x >> 3;
        int c4 = (threadIdx.x & 7) * 4;
        const float* src = w + ((size_t)e * K + k0 + r) * N + n0 + c4;
        float4 v = *(const float4*)src;
        t[r][c4] = v.x; t[r][c4+1] = v.y; t[r][c4+2] = v.z; t[r][c4+3] = v.w;
        __syncthreads();
        int cc = threadIdx.x & 7;
        ushort4 o;
        o.x = f2bf(t[cc*4+0][r]); o.y = f2bf(t[cc*4+1][r]);
        o.z = f2bf(t[cc*4+2][r]); o.w = f2bf(t[cc*4+3][r]);
        *(ushort4*)(wt + ((size_t)e * N + n0 + r) * K + k0 + cc*4) = o;
        return;
    }
    // ---------------- router path ----------------
    int bid = id - NCVT;
    float* g     = smem;                       // [NE*HD] transposed [e][k]
    int*   le    = (int*)&smem[8192];          // [64]
    float* lw    = &smem[8256];                // [64]
    int*   lslot = (int*)&smem[8320];          // [64]
    int*   lcnt  = (int*)&smem[8384];          // [8]
    int*   lbase = (int*)&smem[8392];          // [8]
    for (int i = threadIdx.x; i < NE * HD; i += 256) {
        int k = i >> 3, e = i & 7;
        g[e * HD + k] = gw[i];
    }
    if (threadIdx.x < NE) lcnt[threadIdx.x] = 0;
    __syncthreads();

    int wave = threadIdx.x >> 6, lane = threadIdx.x & 63;
    int t0 = bid * RTOK;
    for (int i = 0; i < RTOK / 4; i++) {
        int tt = wave * (RTOK / 4) + i;
        int t = t0 + tt;
        const float4* xr = (const float4*)(x + (size_t)t * HD);
        float acc[NE];
#pragma unroll
        for (int e = 0; e < NE; e++) acc[e] = 0.f;
#pragma unroll
        for (int j = 0; j < HD / 256; j++) {
            float4 xv = xr[lane + 64 * j];
            ushort4 o4;
            o4.x = f2bf(xv.x); o4.y = f2bf(xv.y);
            o4.z = f2bf(xv.z); o4.w = f2bf(xv.w);
            *(ushort4*)(xb + (size_t)t * HD + (lane + 64 * j) * 4) = o4;
#pragma unroll
            for (int e = 0; e < NE; e++) {
                float4 gv = *(const float4*)&g[e * HD + (lane + 64 * j) * 4];
                acc[e] += xv.x * gv.x + xv.y * gv.y + xv.z * gv.z + xv.w * gv.w;
            }
        }
#pragma unroll
        for (int e = 0; e < NE; e++) {
            float v = acc[e];
#pragma unroll
            for (int off = 32; off > 0; off >>= 1) v += __shfl_down(v, off, 64);
            acc[e] = v;
        }
        if (lane == 0) {
            int e1 = 0; float l1 = acc[0];
#pragma unroll
            for (int e = 1; e < NE; e++) if (acc[e] > l1) { l1 = acc[e]; e1 = e; }
            int e2 = -1; float l2 = -3.0e38f;
#pragma unroll
            for (int e = 0; e < NE; e++) if (e != e1 && acc[e] > l2) { l2 = acc[e]; e2 = e; }
            float w1v = 1.f / (1.f + expf(l2 - l1));  // softmax denom cancels in top-2
            le[tt * 2] = e1;     le[tt * 2 + 1] = e2;
            lw[tt * 2] = w1v;    lw[tt * 2 + 1] = 1.f - w1v;
        }
    }
    __syncthreads();
    if (threadIdx.x < RTOK * 2)
        lslot[threadIdx.x] = atomicAdd(&lcnt[le[threadIdx.x]], 1);
    __syncthreads();
    if (threadIdx.x < NE)
        lbase[threadIdx.x] = atomicAdd(&meta[threadIdx.x * 32], lcnt[threadIdx.x]);
    __syncthreads();
    if (threadIdx.x < RTOK * 2) {
        int gi = t0 * 2 + threadIdx.x;
        int e = le[threadIdx.x];
        tok_e[gi]    = e;
        tok_slot[gi] = lbase[e] + lslot[threadIdx.x];
        tok_w[gi]    = lw[threadIdx.x];
    }
}

// ------------- scatter token ids/weights into compact row space -------------
__global__ __launch_bounds__(256) void scatter_k(const int* __restrict__ meta,
        const int* __restrict__ tok_e, const int* __restrict__ tok_slot,
        const float* __restrict__ tok_w, int* __restrict__ rows_tok,
        float* __restrict__ rows_w) {
    int i = blockIdx.x * 256 + threadIdx.x;     // 0..ROWS-1
    int e = tok_e[i];
    int off = 0;
#pragma unroll
    for (int k = 0; k < NE; k++) {
        int c = meta[k * 32];
        off += (k < e) ? c : 0;
    }
    int r = off + tok_slot[i];
    rows_tok[r] = i >> 1;
    rows_w[r] = tok_w[i];
}

#define SB0()   __builtin_amdgcn_sched_barrier(0)
#define VMW4()  do { asm volatile("s_waitcnt vmcnt(4)" ::: "memory"); SB0(); } while (0)
#define VMW6()  do { asm volatile("s_waitcnt vmcnt(6)" ::: "memory"); SB0(); } while (0)
#define VMW0()  do { asm volatile("s_waitcnt vmcnt(0)" ::: "memory"); SB0(); } while (0)
#define BAR()   do { __builtin_amdgcn_s_barrier(); SB0(); } while (0)
#define PRIO(P) __builtin_amdgcn_s_setprio(P)

// ============ GEMM1: unchanged r10 config (passed, control arm) ============
// 128x128 tile, BK=32, depth-2 ring, 4 waves 64x64, 32 KiB LDS, vmcnt(4).
#define ISSUE1(KK, NT_) do { \
    int kk_ = (KK) < (NT_) ? (KK) : (NT_) - 1; \
    int bb_ = ((KK) & 1) * 4096; \
    GLD16(pa0 + kk_ * 32, &As[bb_ + (w * 64) * 8]); \
    GLD16(pa1 + kk_ * 32, &As[bb_ + (256 + w * 64) * 8]); \
    GLD16(pb0 + kk_ * 32, &Bs[bb_ + (w * 64) * 8]); \
    GLD16(pb1 + kk_ * 32, &Bs[bb_ + (256 + w * 64) * 8]); } while (0)

#define KSTEP1(RB) do { \
    bf16x8 af[4], bfr[4]; \
    _Pragma("unroll") \
    for (int in_ = 0; in_ < 4; in_++) { \
        int row_ = wn * 64 + in_ * 16 + rl; \
        int ph_ = q ^ ((row_ >> 1) & 3); \
        bfr[in_] = *(const bf16x8*)&Bs[(RB) + row_ * 32 + ph_ * 8]; \
    } \
    _Pragma("unroll") \
    for (int im_ = 0; im_ < 4; im_++) { \
        int row_ = wm * 64 + im_ * 16 + rl; \
        int ph_ = q ^ ((row_ >> 1) & 3); \
        af[im_] = *(const bf16x8*)&As[(RB) + row_ * 32 + ph_ * 8]; \
    } \
    _Pragma("unroll") \
    for (int im_ = 0; im_ < 4; im_++) \
    _Pragma("unroll") \
    for (int in_ = 0; in_ < 4; in_++) \
        acc[im_][in_] = __builtin_amdgcn_mfma_f32_16x16x32_bf16( \
            af[im_], bfr[in_], acc[im_][in_], 0, 0, 0); } while (0)

__global__ __launch_bounds__(256, 4) void gemm1_k(
    const unsigned short* __restrict__ Xbf,   // [T][HD]
    const unsigned short* __restrict__ W1T,   // [E][HD2][HD]
    const float* __restrict__ b1,             // [E][HD2]
    const int* __restrict__ meta,
    const int* __restrict__ rows_tok,
    unsigned short* __restrict__ hdn)         // [ROWS][HD2]
{
    __shared__ unsigned short As[2 * 4096];
    __shared__ unsigned short Bs[2 * 4096];
    int id = blockIdx.x;
    int r_ = id & 7, qq = id >> 3;
    int xx = qq & 15, mt = (qq >> 4) * 8 + r_;
    int e, r0, rend;
    tile_locate_g(meta, mt, 7, &e, &r0, &rend);
    if (e < 0) return;
    int n0 = xx * 128;

    int tid = threadIdx.x, w = tid >> 6, lane = tid & 63;
    int wm = w & 1, wn = w >> 1;
    int rl = lane & 15, q = lane >> 4;

    const unsigned short *pa0, *pa1, *pb0, *pb1;
    {
        int gg = tid, row = gg >> 2, lc = (gg & 3) ^ ((row >> 1) & 3);
        int grow = r0 + row; grow = grow < ROWS - 1 ? grow : ROWS - 1;
        pa0 = Xbf + (size_t)rows_tok[grow] * HD + lc * 8;
        pb0 = W1T + ((size_t)e * HD2 + n0 + row) * HD + lc * 8;
        gg = 256 + tid; row = gg >> 2; lc = (gg & 3) ^ ((row >> 1) & 3);
        grow = r0 + row; grow = grow < ROWS - 1 ? grow : ROWS - 1;
        pa1 = Xbf + (size_t)rows_tok[grow] * HD + lc * 8;
        pb1 = W1T + ((size_t)e * HD2 + n0 + row) * HD + lc * 8;
    }

    f32x4 acc[4][4];
#pragma unroll
    for (int a = 0; a < 4; a++)
#pragma unroll
    for (int b = 0; b < 4; b++)
        acc[a][b] = (f32x4){0.f, 0.f, 0.f, 0.f};

    ISSUE1(0, HD / 32);

#pragma unroll 2
    for (int kt = 0; kt < HD / 32; kt++) {
        ISSUE1(kt + 1, HD / 32);
        SB0();
        VMW4();
        BAR();
        PRIO(1);
        KSTEP1((kt & 1) * 4096);
        PRIO(0);
        BAR();
    }
    VMW0();
    BAR();

    // epilogue: bias+relu -> LDS bounce -> coalesced 256B-run stores
    {
        const float* b1e = b1 + (size_t)e * HD2;
        unsigned short* obuf = wn ? (unsigned short*)Bs : (unsigned short*)As;
#pragma unroll
        for (int in = 0; in < 4; in++) {
            int ci = in * 16 + rl;
            float bias = b1e[n0 + wn * 64 + ci];
#pragma unroll
            for (int im = 0; im < 4; im++) {
                int rowb = wm * 64 + im * 16 + q * 4;
#pragma unroll
                for (int j = 0; j < 4; j++) {
                    int row = rowb + j;
                    float v = acc[im][in][j] + bias;
                    v = v > 0.f ? v : 0.f;
                    int gc = ci >> 3;
                    obuf[row * 64 + (((gc ^ (row & 7)) << 3) | (ci & 7))] = f2bf(v);
                }
            }
        }
    }
    BAR();
#pragma unroll
    for (int it = 0; it < 8; it++) {
        int row = it * 16 + (tid >> 4);
        int gran = tid & 15;
        const unsigned short* ibuf = (gran < 8) ? (const unsigned short*)As
                                                : (const unsigned short*)Bs;
        u16x8 v = *(const u16x8*)&ibuf[row * 64 + (((gran & 7) ^ (row & 7)) << 3)];
        int r = r0 + row;
        if (r < rend)
            *(u16x8*)&hdn[(size_t)r * HD2 + n0 + gran * 8] = v;
    }
}

// ============ GEMM2: 256x128 block, 4 waves of 128x64 (intensity arm) ============
// FLOP/LDS-byte 32 -> 43.7 (A-frags amortized over 2x output). Depth-2 ring:
// A slot 8192 elem (256x32), B slot 4096 elem (128x32); 48 KiB total; 2 blk/CU
// (VGPR ~200). Per iter: 6 GLD16/thread, vmcnt(6) retires current tile exactly.
// Same swizzle phys granule = g ^ ((row>>1)&3) (per-instruction read pattern
// identical to r10's measured-0-conflict pattern).
#define ISSUE2(KK, NT_) do { \
    int kk_ = (KK) < (NT_) ? (KK) : (NT_) - 1; \
    int ba_ = ((KK) & 1) * 8192; \
    int bb_ = ((KK) & 1) * 4096; \
    GLD16(pa[0] + kk_ * 32, &As[ba_ + (w * 64) * 8]); \
    GLD16(pa[1] + kk_ * 32, &As[ba_ + (256 + w * 64) * 8]); \
    GLD16(pa[2] + kk_ * 32, &As[ba_ + (512 + w * 64) * 8]); \
    GLD16(pa[3] + kk_ * 32, &As[ba_ + (768 + w * 64) * 8]); \
    GLD16(pb[0] + kk_ * 32, &Bs[bb_ + (w * 64) * 8]); \
    GLD16(pb[1] + kk_ * 32, &Bs[bb_ + (256 + w * 64) * 8]); } while (0)

#define KSTEP2(RA, RB) do { \
    bf16x8 af[8], bfr[4]; \
    _Pragma("unroll") \
    for (int in_ = 0; in_ < 4; in_++) { \
        int row_ = wn * 64 + in_ * 16 + rl; \
        int ph_ = q ^ ((row_ >> 1) & 3); \
        bfr[in_] = *(const bf16x8*)&Bs[(RB) + row_ * 32 + ph_ * 8]; \
    } \
    _Pragma("unroll") \
    for (int im_ = 0; im_ < 8; im_++) { \
        int row_ = wm * 128 + im_ * 16 + rl; \
        int ph_ = q ^ ((row_ >> 1) & 3); \
        af[im_] = *(const bf16x8*)&As[(RA) + row_ * 32 + ph_ * 8]; \
    } \
    _Pragma("unroll") \
    for (int im_ = 0; im_ < 8; im_++) \
    _Pragma("unroll") \
    for (int in_ = 0; in_ < 4; in_++) \
        acc[im_][in_] = __builtin_amdgcn_mfma_f32_16x16x32_bf16( \
            af[im_], bfr[in_], acc[im_][in_], 0, 0, 0); } while (0)

__global__ __launch_bounds__(256, 2) void gemm2_k(
    const unsigned short* __restrict__ hdn,   // [ROWS][HD2]
    const unsigned short* __restrict__ W2T,   // [E][HD][HD2]
    const float* __restrict__ b2,             // [E][HD]
    const int* __restrict__ meta,
    const int* __restrict__ rows_tok,
    const float* __restrict__ rows_w,
    float* __restrict__ out)                  // [T][HD]
{
    __shared__ unsigned short As[2 * 8192];   // 32 KiB: 256 rows x 32 k, dbuf
    __shared__ unsigned short Bs[2 * 4096];   // 16 KiB: 128 rows x 32 k, dbuf
    // XCD-affinity decode: all 8 N-blocks of one 256-row M-tile share r=id&7
    int id = blockIdx.x;
    int r_ = id & 7, qq = id >> 3;
    int xx = qq & 7, mt = (qq >> 3) * 8 + r_;
    int e, r0, rend;
    tile_locate_g(meta, mt, 8, &e, &r0, &rend);
    if (e < 0) return;
    int n0 = xx * 128;

    int tid = threadIdx.x, w = tid >> 6, lane = tid & 63;
    int wm = w & 1, wn = w >> 1;
    int rl = lane & 15, q = lane >> 4;

    // staging sources: A 4 chunks (256 rows), B 2 chunks (128 rows), pre-swizzled
    const unsigned short* pa[4];
    const unsigned short* pb[2];
#pragma unroll
    for (int c = 0; c < 4; c++) {
        int gg = c * 256 + tid, row = gg >> 2, lc = (gg & 3) ^ ((row >> 1) & 3);
        int grow = r0 + row; grow = grow < ROWS - 1 ? grow : ROWS - 1;
        pa[c] = hdn + (size_t)grow * HD2 + lc * 8;
    }
#pragma unroll
    for (int c = 0; c < 2; c++) {
        int gg = c * 256 + tid, row = gg >> 2, lc = (gg & 3) ^ ((row >> 1) & 3);
        pb[c] = W2T + ((size_t)e * HD + n0 + row) * HD2 + lc * 8;
    }

    f32x4 acc[8][4];
#pragma unroll
    for (int a = 0; a < 8; a++)
#pragma unroll
    for (int b = 0; b < 4; b++)
        acc[a][b] = (f32x4){0.f, 0.f, 0.f, 0.f};

    ISSUE2(0, HD2 / 32);

#pragma unroll 2
    for (int kt = 0; kt < HD2 / 32; kt++) {
        ISSUE2(kt + 1, HD2 / 32);
        SB0();
        VMW6();                    // retires tile kt's 6 loads (12 -> 6)
        BAR();
        PRIO(1);
        KSTEP2((kt & 1) * 8192, (kt & 1) * 4096);
        PRIO(0);
        BAR();
    }
    VMW0();                        // drain tail (LDS freed at exit)

    // epilogue: (acc + bias) * row_weight, atomic scatter (rows >= rend masked)
    const float* b2e = b2 + (size_t)e * HD;
    float bias[4];
#pragma unroll
    for (int in = 0; in < 4; in++)
        bias[in] = b2e[n0 + wn * 64 + in * 16 + rl];
#pragma unroll
    for (int im = 0; im < 8; im++) {
        int rb2 = r0 + wm * 128 + im * 16 + q * 4;
#pragma unroll
        for (int j = 0; j < 4; j++) {
            int r = rb2 + j;
            if (r < rend) {
                int tok = rows_tok[r];
                float wt = rows_w[r];
                float* op = out + (size_t)tok * HD + n0 + wn * 64;
#pragma unroll
                for (int in = 0; in < 4; in++) {
                    float v = (acc[im][in][j] + bias[in]) * wt;
                    atomicAdd(op + in * 16 + rl, v);
                }
            }
        }
    }
}

extern "C" void kernel_launch(void* const* d_in, const int* in_sizes, int n_in,
                              void* d_out, int out_size, void* d_ws, size_t ws_size,
                              hipStream_t stream) {
    const float* x  = (const float*)d_in[0];
    const float* gw = (const float*)d_in[1];
    const float* w1 = (const float*)d_in[2];
    const float* b1 = (const float*)d_in[3];
    const float* w2 = (const float*)d_in[4];
    const float* b2 = (const float*)d_in[5];
    float* out = (float*)d_out;

    uint8_t* ws = (uint8_t*)d_ws;
    unsigned short* Xbf = (unsigned short*)(ws);                  // 32 MiB
    unsigned short* W1T = (unsigned short*)(ws + 33554432ull);    // 32 MiB
    unsigned short* W2T = (unsigned short*)(ws + 67108864ull);    // 32 MiB
    unsigned short* HDN = (unsigned short*)(ws + 100663296ull);   // 128 MiB
    int*   meta     = (int*)(ws + 234881024ull);
    int*   tok_e    = meta + 2048;
    int*   tok_slot = tok_e + ROWS;
    float* tok_w    = (float*)(tok_slot + ROWS);
    int*   rows_tok = (int*)(tok_w + ROWS);
    float* rows_w   = (float*)(rows_tok + ROWS);

    hipMemsetAsync(meta, 0, 1024, stream);   // zero padded counters
    hipMemsetAsync(d_out, 0, (size_t)out_size * sizeof(float), stream);

    front_k<<<NCVT + T_TOK / RTOK, 256, 0, stream>>>(w1, w2, W1T, W2T,
                                                     x, gw, meta, tok_e, tok_slot,
                                                     tok_w, Xbf);
    scatter_k<<<ROWS / 256, 256, 0, stream>>>(meta, tok_e, tok_slot, tok_w,
                                              rows_tok, rows_w);
    gemm1_k<<<16 * MAXT, 256, 0, stream>>>(Xbf, W1T, b1, meta, rows_tok, HDN);
    gemm2_k<<<8 * MT256, 256, 0, stream>>>(HDN, W2T, b2, meta, rows_tok, rows_w, out);
}